// Round 1
// baseline (4775.393 us; speedup 1.0000x reference)
//
#include <hip/hip_runtime.h>
#include <math.h>

#define HMM_B 32
#define HMM_T 8192
#define HMM_K 64

// broadcast lane 0's value to all lanes (uniform scalar, ~free)
__device__ __forceinline__ float bcast0(float v) {
    return __int_as_float(__builtin_amdgcn_readfirstlane(__float_as_int(v)));
}

// u_i = sum_j A[i][j] * w[j] ; areg fully register-resident, wv is LDS broadcast
__device__ __forceinline__ float matvec_row(const float* areg, const float4* wv) {
    float a0 = 0.f, a1 = 0.f, a2 = 0.f, a3 = 0.f;
    #pragma unroll
    for (int j = 0; j < 16; ++j) {
        float4 w4 = wv[j];
        a0 = fmaf(areg[4 * j + 0], w4.x, a0);
        a1 = fmaf(areg[4 * j + 1], w4.y, a1);
        a2 = fmaf(areg[4 * j + 2], w4.z, a2);
        a3 = fmaf(areg[4 * j + 3], w4.w, a3);
    }
    return (a0 + a1) + (a2 + a3);
}

// blocks 0..B-1: forward pass, writes shifted ln_f into f_out [B,T,K]
// blocks B..2B-1: backward pass, writes shifted ln_b into b_out [B,T,K]
__global__ void __launch_bounds__(64, 1)
hmm_recur(const float* __restrict__ obvs,
          const float* __restrict__ log_init,
          const float* __restrict__ transfer,
          const float* __restrict__ means,
          const float* __restrict__ log_stds,
          float* __restrict__ f_out,
          float* __restrict__ b_out)
{
    __shared__ float wbuf[2][HMM_K];
    const int lane = threadIdx.x;
    const int blk  = blockIdx.x;
    const bool fwd = (blk < HMM_B);
    const int b    = fwd ? blk : blk - HMM_B;

    const float mean_k  = means[lane];
    const float ls      = log_stds[lane];
    const float inv_std = __expf(-ls);
    const float ce      = -ls - 0.91893853320467274f;  // -log_std - 0.5*log(2pi)
    const float li      = log_init[lane];

    float areg[HMM_K];
    #pragma unroll
    for (int j = 0; j < HMM_K; ++j) areg[j] = transfer[lane * HMM_K + j];

    const float* __restrict__ orow = obvs + (size_t)b * HMM_T;

    if (fwd) {
        float x = orow[0];
        float z = (x - mean_k) * inv_std;
        float v = fmaf(-0.5f * z, z, ce) + li;
        f_out[((size_t)b * HMM_T) * HMM_K + lane] = v;
        for (int t = 1; t < HMM_T; ++t) {
            float shift = bcast0(v);
            float d = fminf(v - shift, 75.0f);   // spread structurally bounded; clamp = safety
            float w = __expf(d);
            const int p = t & 1;
            wbuf[p][lane] = w;
            __syncthreads();
            float u = matvec_row(areg, (const float4*)wbuf[p]);
            float xt = orow[t];
            float zt = (xt - mean_k) * inv_std;
            v = fmaf(-0.5f * zt, zt, ce) + __logf(u);
            f_out[((size_t)b * HMM_T + t) * HMM_K + lane] = v;
        }
    } else {
        float bb = li;  // b_{T-1} = log_initial_probs (per reference)
        b_out[((size_t)b * HMM_T + (HMM_T - 1)) * HMM_K + lane] = bb;
        for (int t = HMM_T - 2; t >= 0; --t) {
            float xt = orow[t + 1];
            float zt = (xt - mean_k) * inv_std;
            float tmp = bb + fmaf(-0.5f * zt, zt, ce);  // b_{t+1} + e_{t+1}
            float shift = bcast0(tmp);
            float d = fminf(tmp - shift, 75.0f);
            float w = __expf(d);
            const int p = t & 1;
            wbuf[p][lane] = w;
            __syncthreads();
            float u = matvec_row(areg, (const float4*)wbuf[p]);
            bb = __logf(u);
            b_out[((size_t)b * HMM_T + t) * HMM_K + lane] = bb;
        }
    }
}

// gamma = f + b - logsumexp_k(f + b); one wave per (b,t) row; in-place on f buffer ok
__global__ void __launch_bounds__(256)
hmm_combine(const float* __restrict__ fbuf,
            const float* __restrict__ bbuf,
            float* __restrict__ out)
{
    const size_t row = (size_t)blockIdx.x * 4 + (threadIdx.x >> 6);
    const int lane = threadIdx.x & 63;
    const size_t idx = row * HMM_K + lane;
    float g = fbuf[idx] + bbuf[idx];
    float m = g;
    #pragma unroll
    for (int off = 32; off > 0; off >>= 1) m = fmaxf(m, __shfl_xor(m, off));
    float e = __expf(g - m);
    float s = e;
    #pragma unroll
    for (int off = 32; off > 0; off >>= 1) s += __shfl_xor(s, off);
    out[idx] = (g - m) - __logf(s);
}

// Fallback when ws too small: backward recurrence fused with combine, in-place on d_out.
__global__ void __launch_bounds__(64, 1)
hmm_bwd_combine(const float* __restrict__ obvs,
                const float* __restrict__ log_init,
                const float* __restrict__ transfer,
                const float* __restrict__ means,
                const float* __restrict__ log_stds,
                float* __restrict__ fout)
{
    __shared__ float wbuf[2][HMM_K];
    const int lane = threadIdx.x;
    const int b = blockIdx.x;
    const float mean_k  = means[lane];
    const float ls      = log_stds[lane];
    const float inv_std = __expf(-ls);
    const float ce      = -ls - 0.91893853320467274f;
    const float li      = log_init[lane];
    float areg[HMM_K];
    #pragma unroll
    for (int j = 0; j < HMM_K; ++j) areg[j] = transfer[lane * HMM_K + j];
    const float* __restrict__ orow = obvs + (size_t)b * HMM_T;

    float bb = li;
    for (int t = HMM_T - 1; t >= 0; --t) {
        const size_t base = ((size_t)b * HMM_T + t) * HMM_K;
        float g = fout[base + lane] + bb;
        float m = g;
        #pragma unroll
        for (int off = 32; off > 0; off >>= 1) m = fmaxf(m, __shfl_xor(m, off));
        float e = __expf(g - m);
        float s = e;
        #pragma unroll
        for (int off = 32; off > 0; off >>= 1) s += __shfl_xor(s, off);
        fout[base + lane] = (g - m) - __logf(s);
        if (t > 0) {
            float xt = orow[t];
            float zt = (xt - mean_k) * inv_std;
            float tmp = bb + fmaf(-0.5f * zt, zt, ce);  // b_t + e_t -> b_{t-1}
            float shift = bcast0(tmp);
            float d = fminf(tmp - shift, 75.0f);
            float w = __expf(d);
            const int p = t & 1;
            wbuf[p][lane] = w;
            __syncthreads();
            bb = __logf(matvec_row(areg, (const float4*)wbuf[p]));
        }
    }
}

extern "C" void kernel_launch(void* const* d_in, const int* in_sizes, int n_in,
                              void* d_out, int out_size, void* d_ws, size_t ws_size,
                              hipStream_t stream)
{
    const float* obvs     = (const float*)d_in[0];
    const float* log_init = (const float*)d_in[1];
    const float* transfer = (const float*)d_in[2];
    const float* means    = (const float*)d_in[3];
    const float* log_stds = (const float*)d_in[4];
    float* out = (float*)d_out;

    const size_t need = (size_t)HMM_B * HMM_T * HMM_K * sizeof(float);
    if (ws_size >= need) {
        float* bws = (float*)d_ws;
        // fwd (blocks 0..31) and bwd (blocks 32..63) run concurrently
        hipLaunchKernelGGL(hmm_recur, dim3(2 * HMM_B), dim3(HMM_K), 0, stream,
                           obvs, log_init, transfer, means, log_stds, out, bws);
        hipLaunchKernelGGL(hmm_combine, dim3(HMM_B * HMM_T / 4), dim3(256), 0, stream,
                           out, bws, out);
    } else {
        // serial fallback: fwd into d_out, then bwd fused with combine in-place
        hipLaunchKernelGGL(hmm_recur, dim3(HMM_B), dim3(HMM_K), 0, stream,
                           obvs, log_init, transfer, means, log_stds, out, out);
        hipLaunchKernelGGL(hmm_bwd_combine, dim3(HMM_B), dim3(HMM_K), 0, stream,
                           obvs, log_init, transfer, means, log_stds, out);
    }
}

// Round 2
// 2246.941 us; speedup vs baseline: 2.1253x; 2.1253x over previous
//
#include <hip/hip_runtime.h>
#include <math.h>

#define HMM_B 32
#define HMM_T 8192
#define HMM_K 64

typedef float f2 __attribute__((ext_vector_type(2)));

#define LN2F 0.69314718055994531f
#define INV_LN2F 1.4426950408889634f
#define HALF_INV_LN2_SQRTF 0.8493218002880191f  /* sqrt(0.5/ln2) */
#define NEG_HALF_LOG_2PI 0.91893853320467274f

// broadcast lane 0's value (uniform scalar via SGPR)
__device__ __forceinline__ float bcast0(float v) {
    return __int_as_float(__builtin_amdgcn_readfirstlane(__float_as_int(v)));
}
// raw transcendentals (base-2), no libm range handling
__device__ __forceinline__ float exp2_fast(float x) {
    float r; asm("v_exp_f32 %0, %1" : "=v"(r) : "v"(x)); return r;
}
__device__ __forceinline__ float log2_fast(float x) {
    float r; asm("v_log_f32 %0, %1" : "=v"(r) : "v"(x)); return r;
}

// u_i = sum_j A[i][j]*w[j]; A register-resident as float2 pairs -> v_pk_fma_f32
__device__ __forceinline__ float matvec_row(const f2* __restrict__ areg,
                                            const float4* __restrict__ wv) {
    f2 a0 = {0.f, 0.f}, a1 = {0.f, 0.f}, a2 = {0.f, 0.f}, a3 = {0.f, 0.f};
    #pragma unroll
    for (int j = 0; j < 8; ++j) {
        float4 wA = wv[2 * j];
        float4 wB = wv[2 * j + 1];
        f2 wa01; wa01.x = wA.x; wa01.y = wA.y;
        f2 wa23; wa23.x = wA.z; wa23.y = wA.w;
        f2 wb01; wb01.x = wB.x; wb01.y = wB.y;
        f2 wb23; wb23.x = wB.z; wb23.y = wB.w;
        a0 += areg[4 * j + 0] * wa01;
        a1 += areg[4 * j + 1] * wa23;
        a2 += areg[4 * j + 2] * wb01;
        a3 += areg[4 * j + 3] * wb23;
    }
    f2 s = (a0 + a1) + (a2 + a3);
    return s.x + s.y;
}

// blocks 0..B-1: forward (writes shifted log2-f into f_out [B,T,K])
// blocks B..2B-1: backward (writes shifted log2-b into b_out [B,T,K])
// Single wave per block; NO in-loop barriers (wave-ordered LDS), stores never drained.
__global__ void __launch_bounds__(64, 1)
hmm_recur(const float* __restrict__ obvs,
          const float* __restrict__ log_init,
          const float* __restrict__ transfer,
          const float* __restrict__ means,
          const float* __restrict__ log_stds,
          float* __restrict__ f_out,
          float* __restrict__ b_out)
{
    __shared__ float4 wbuf4[16];
    __shared__ float obs_lds[HMM_T + 4];   // +4 pad: t+1 prefetch may read index T (unused)
    const int lane = threadIdx.x;
    const int blk  = blockIdx.x;
    const bool fwd = (blk < HMM_B);
    const int b    = fwd ? blk : blk - HMM_B;

    const float mean_k   = means[lane];
    const float ls       = log_stds[lane];
    const float inv_std2 = __expf(-ls) * HALF_INV_LN2_SQRTF; // z' = (x-mean)*inv_std2 ; e2 = -z'^2 + ce2
    const float ce2      = (-ls - NEG_HALF_LOG_2PI) * INV_LN2F;
    const float li2      = log_init[lane] * INV_LN2F;

    f2 areg[32];
    const f2* Arow = (const f2*)(transfer + lane * HMM_K);
    #pragma unroll
    for (int j = 0; j < 32; ++j) areg[j] = Arow[j];

    const float* __restrict__ orow = obvs + (size_t)b * HMM_T;
    {
        const float4* o4 = (const float4*)orow;
        float4* l4 = (float4*)obs_lds;
        #pragma unroll 4
        for (int i = lane; i < HMM_T / 4; i += 64) l4[i] = o4[i];
    }
    __syncthreads();   // one-time drain (single wave -> waitcnt only)

    float* wbs = ((float*)wbuf4) + lane;

    if (fwd) {
        float x0 = obs_lds[0];
        float z0 = (x0 - mean_k) * inv_std2;
        float v  = fmaf(-z0, z0, ce2) + li2;
        float* po = f_out + (size_t)b * HMM_T * HMM_K + lane;
        *po = v;
        float x1 = obs_lds[1];
        float z1 = (x1 - mean_k) * inv_std2;
        float e2c = fmaf(-z1, z1, ce2);
        for (int t = 1; t < HMM_T; ++t) {
            float shift = bcast0(v);
            float d = fminf(v - shift, 100.0f);   // spread structurally bounded (<~65); safety clamp
            float w = exp2_fast(d);
            *wbs = w;                             // ds_write; wave-ordered vs reads below
            __builtin_amdgcn_wave_barrier();
            float xn = obs_lds[t + 1];            // prefetch next emission during matvec wait
            float zn = (xn - mean_k) * inv_std2;
            float e2n = fmaf(-zn, zn, ce2);
            float u = matvec_row(areg, wbuf4);
            __builtin_amdgcn_wave_barrier();
            v = e2c + log2_fast(u);
            po += HMM_K;
            *po = v;                              // fire-and-forget global store
            e2c = e2n;
        }
    } else {
        float bb = li2;                           // b_{T-1} = log_initial_probs
        float* po = b_out + ((size_t)b * HMM_T + (HMM_T - 1)) * HMM_K + lane;
        *po = bb;
        float xT = obs_lds[HMM_T - 1];
        float zT = (xT - mean_k) * inv_std2;
        float e2c = fmaf(-zT, zT, ce2);           // e2 for t+1 = T-1
        for (int t = HMM_T - 2; t >= 0; --t) {
            float tmp = bb + e2c;                 // b_{t+1} + e_{t+1}  (log2 units)
            float shift = bcast0(tmp);
            float d = fminf(tmp - shift, 100.0f);
            float w = exp2_fast(d);
            *wbs = w;
            __builtin_amdgcn_wave_barrier();
            float xn = obs_lds[t];                // emission for NEXT iteration (index (t-1)+1)
            float zn = (xn - mean_k) * inv_std2;
            float e2n = fmaf(-zn, zn, ce2);
            float u = matvec_row(areg, wbuf4);
            __builtin_amdgcn_wave_barrier();
            bb = log2_fast(u);
            po -= HMM_K;
            *po = bb;
            e2c = e2n;
        }
    }
}

// gamma = ln2 * (g2 - m - log2(sum exp2(g2 - m))), g2 = f2+b2 (log2-domain inputs)
__global__ void __launch_bounds__(256)
hmm_combine(const float* __restrict__ fbuf,
            const float* __restrict__ bbuf,
            float* __restrict__ out)
{
    const size_t row = (size_t)blockIdx.x * 4 + (threadIdx.x >> 6);
    const int lane = threadIdx.x & 63;
    const size_t idx = row * HMM_K + lane;
    float g = fbuf[idx] + bbuf[idx];
    float m = g;
    #pragma unroll
    for (int off = 32; off > 0; off >>= 1) m = fmaxf(m, __shfl_xor(m, off));
    float e = exp2_fast(g - m);
    float s = e;
    #pragma unroll
    for (int off = 32; off > 0; off >>= 1) s += __shfl_xor(s, off);
    out[idx] = LN2F * ((g - m) - log2_fast(s));
}

// Fallback (ws too small): bwd fused with combine, in-place on d_out (f in log2 units).
__global__ void __launch_bounds__(64, 1)
hmm_bwd_combine(const float* __restrict__ obvs,
                const float* __restrict__ log_init,
                const float* __restrict__ transfer,
                const float* __restrict__ means,
                const float* __restrict__ log_stds,
                float* __restrict__ fout)
{
    __shared__ float4 wbuf4[16];
    __shared__ float obs_lds[HMM_T + 4];
    const int lane = threadIdx.x;
    const int b = blockIdx.x;
    const float mean_k   = means[lane];
    const float ls       = log_stds[lane];
    const float inv_std2 = __expf(-ls) * HALF_INV_LN2_SQRTF;
    const float ce2      = (-ls - NEG_HALF_LOG_2PI) * INV_LN2F;
    const float li2      = log_init[lane] * INV_LN2F;
    f2 areg[32];
    const f2* Arow = (const f2*)(transfer + lane * HMM_K);
    #pragma unroll
    for (int j = 0; j < 32; ++j) areg[j] = Arow[j];
    const float* __restrict__ orow = obvs + (size_t)b * HMM_T;
    {
        const float4* o4 = (const float4*)orow;
        float4* l4 = (float4*)obs_lds;
        #pragma unroll 4
        for (int i = lane; i < HMM_T / 4; i += 64) l4[i] = o4[i];
    }
    __syncthreads();
    float* wbs = ((float*)wbuf4) + lane;

    float bb = li2;
    for (int t = HMM_T - 1; t >= 0; --t) {
        const size_t base = ((size_t)b * HMM_T + t) * HMM_K;
        float g = fout[base + lane] + bb;
        float m = g;
        #pragma unroll
        for (int off = 32; off > 0; off >>= 1) m = fmaxf(m, __shfl_xor(m, off));
        float e = exp2_fast(g - m);
        float s = e;
        #pragma unroll
        for (int off = 32; off > 0; off >>= 1) s += __shfl_xor(s, off);
        fout[base + lane] = LN2F * ((g - m) - log2_fast(s));
        if (t > 0) {
            float xt = obs_lds[t];
            float zt = (xt - mean_k) * inv_std2;
            float tmp = bb + fmaf(-zt, zt, ce2);
            float shift = bcast0(tmp);
            float d = fminf(tmp - shift, 100.0f);
            float w = exp2_fast(d);
            *wbs = w;
            __builtin_amdgcn_wave_barrier();
            float u = matvec_row(areg, wbuf4);
            __builtin_amdgcn_wave_barrier();
            bb = log2_fast(u);
        }
    }
}

extern "C" void kernel_launch(void* const* d_in, const int* in_sizes, int n_in,
                              void* d_out, int out_size, void* d_ws, size_t ws_size,
                              hipStream_t stream)
{
    const float* obvs     = (const float*)d_in[0];
    const float* log_init = (const float*)d_in[1];
    const float* transfer = (const float*)d_in[2];
    const float* means    = (const float*)d_in[3];
    const float* log_stds = (const float*)d_in[4];
    float* out = (float*)d_out;

    const size_t need = (size_t)HMM_B * HMM_T * HMM_K * sizeof(float);
    if (ws_size >= need) {
        float* bws = (float*)d_ws;
        hipLaunchKernelGGL(hmm_recur, dim3(2 * HMM_B), dim3(HMM_K), 0, stream,
                           obvs, log_init, transfer, means, log_stds, out, bws);
        hipLaunchKernelGGL(hmm_combine, dim3(HMM_B * HMM_T / 4), dim3(256), 0, stream,
                           out, bws, out);
    } else {
        hipLaunchKernelGGL(hmm_recur, dim3(HMM_B), dim3(HMM_K), 0, stream,
                           obvs, log_init, transfer, means, log_stds, out, out);
        hipLaunchKernelGGL(hmm_bwd_combine, dim3(HMM_B), dim3(HMM_K), 0, stream,
                           obvs, log_init, transfer, means, log_stds, out);
    }
}